// Round 2
// baseline (147.546 us; speedup 1.0000x reference)
//
#include <hip/hip_runtime.h>

#define BB 8
#define NN 1024
#define DM 256
#define HH 8
#define HD 32
#define TC 768   // 3*DM

typedef __bf16 bf16x8 __attribute__((ext_vector_type(8)));
typedef __bf16 bf16x4 __attribute__((ext_vector_type(4)));
typedef __bf16 bf16x2 __attribute__((ext_vector_type(2)));
typedef float  f32x4  __attribute__((ext_vector_type(4)));
typedef int    i32x4  __attribute__((ext_vector_type(4)));
typedef unsigned int u32;

// ---------------- precast: x -> bf16, W -> W^T bf16 ----------------
__global__ __launch_bounds__(256) void precast(
    const float* __restrict__ x, const float* __restrict__ W,
    __bf16* __restrict__ xb, __bf16* __restrict__ Wt)
{
  const int tid = threadIdx.x;
  const int bid = blockIdx.x;
  if (bid < 48) {
    __shared__ __bf16 T[64][65];
    const int ct = bid % 12, kt = bid / 12;
    const int c0 = ct * 64, k0 = kt * 64;
    #pragma unroll
    for (int i = 0; i < 16; ++i) {         // read coalesced along c
      int e = tid + i * 256, kk = e >> 6, cc = e & 63;
      T[cc][kk] = (__bf16)W[(size_t)(k0 + kk) * TC + c0 + cc];
    }
    __syncthreads();
    #pragma unroll
    for (int i = 0; i < 16; ++i) {         // write coalesced along k
      int e = tid + i * 256, cc = e >> 6, kk = e & 63;
      Wt[(size_t)(c0 + cc) * DM + k0 + kk] = T[cc][kk];
    }
  } else {
    const size_t e = (size_t)(bid - 48) * 256 + tid;   // float4 index
    const float4 v = ((const float4*)x)[e];
    bf16x4 o;
    o[0] = (__bf16)v.x; o[1] = (__bf16)v.y;
    o[2] = (__bf16)v.z; o[3] = (__bf16)v.w;
    ((bf16x4*)xb)[e] = o;
  }
}

// ---------------- QKV projection (R11): global_load_lds + BK=64 ------------
// LDS layout: A-tile [128][64] bf16, B-tile [64][64] bf16, 16B chunks
// swizzled: LDS slot (row, s) holds global chunk s ^ (row&7).
// Staged via global_load_lds dwordx4 (linear dest, pre-swizzled source).
__global__ __launch_bounds__(256, 3) void qkv_gemm(
    const __bf16* __restrict__ xb, const __bf16* __restrict__ Wt,
    const float* __restrict__ bias, __bf16* __restrict__ Qb,
    __bf16* __restrict__ Kb, __bf16* __restrict__ Vt)
{
  __shared__ __align__(16) char LDSU[49152];
  __bf16* As0 = (__bf16*)LDSU;             // 16 KB
  __bf16* Bs0 = (__bf16*)(LDSU + 16384);   //  8 KB
  __bf16* As1 = (__bf16*)(LDSU + 24576);   // 16 KB
  __bf16* Bs1 = (__bf16*)(LDSU + 40960);   //  8 KB

  const int tid  = threadIdx.x;
  const int w    = tid >> 6, lane = tid & 63;
  const int n16  = lane & 15, quad = lane >> 4;
  const int m0   = blockIdx.y * 128, c0 = blockIdx.x * 64;
  const int bb   = m0 >> 10, n0 = m0 & 1023;

  // staging: per instr, 256 threads stage 32 rows x 8 chunks of 16B.
  // thread: row = i*32 + w*8 + (lane>>3); lds slot = lane&7;
  // global chunk g = slot ^ (row&7) = (lane&7) ^ (lane>>3).
  const int stRow = w*8 + (lane >> 3);
  const int stG   = (lane & 7) ^ (lane >> 3);
  const __bf16* gA = &xb[(size_t)(m0 + stRow)*DM + stG*8];
  const __bf16* gB = &Wt[(size_t)(c0 + stRow)*DM + stG*8];

#define QKV_STAGE(Adst, Bdst, K0) do {                                        \
    _Pragma("unroll")                                                         \
    for (int i_ = 0; i_ < 4; ++i_) {                                          \
      const __bf16* gp_ = gA + (size_t)(i_*32)*DM + (K0);                     \
      __bf16* lp_ = (Adst) + (i_*32 + w*8)*64;                                \
      __builtin_amdgcn_global_load_lds(                                       \
          (const __attribute__((address_space(1))) u32*)gp_,                  \
          (__attribute__((address_space(3))) u32*)lp_, 16, 0, 0);             \
    }                                                                         \
    _Pragma("unroll")                                                         \
    for (int i_ = 0; i_ < 2; ++i_) {                                          \
      const __bf16* gp_ = gB + (size_t)(i_*32)*DM + (K0);                     \
      __bf16* lp_ = (Bdst) + (i_*32 + w*8)*64;                                \
      __builtin_amdgcn_global_load_lds(                                       \
          (const __attribute__((address_space(1))) u32*)gp_,                  \
          (__attribute__((address_space(3))) u32*)lp_, 16, 0, 0);             \
    }                                                                         \
  } while (0)

  f32x4 acc[2][4] = {};

  QKV_STAGE(As0, Bs0, 0);
  __syncthreads();

  #pragma unroll
  for (int kk = 0; kk < 4; ++kk) {
    __bf16* Ac = (kk & 1) ? As1 : As0;
    __bf16* Bc = (kk & 1) ? Bs1 : Bs0;
    if (kk == 0)      QKV_STAGE(As1, Bs1, 64);
    else if (kk == 1) QKV_STAGE(As0, Bs0, 128);
    else if (kk == 2) QKV_STAGE(As1, Bs1, 192);
    #pragma unroll
    for (int ks = 0; ks < 2; ++ks) {
      const int ch = ((ks*4 + quad) ^ (n16 & 7)) * 8;   // bf16 offset in row
      bf16x8 af0 = *(const bf16x8*)&Ac[(w*32 + n16)*64 + ch];
      bf16x8 af1 = *(const bf16x8*)&Ac[(w*32 + 16 + n16)*64 + ch];
      #pragma unroll
      for (int cb = 0; cb < 4; ++cb) {
        bf16x8 bfb = *(const bf16x8*)&Bc[(cb*16 + n16)*64 + ch];
        acc[0][cb] = __builtin_amdgcn_mfma_f32_16x16x32_bf16(af0, bfb, acc[0][cb], 0, 0, 0);
        acc[1][cb] = __builtin_amdgcn_mfma_f32_16x16x32_bf16(af1, bfb, acc[1][cb], 0, 0, 0);
      }
    }
    __syncthreads();
  }

  float bv[4];
  #pragma unroll
  for (int cb = 0; cb < 4; ++cb) bv[cb] = bias[c0 + cb*16 + n16];

  if (c0 < 512) {
    __bf16* Ct = (__bf16*)LDSU;
    #pragma unroll
    for (int cb = 0; cb < 4; ++cb)
      #pragma unroll
      for (int mb = 0; mb < 2; ++mb)
        #pragma unroll
        for (int r = 0; r < 4; ++r)
          Ct[(w*32 + mb*16 + quad*4 + r)*72 + cb*16 + n16] =
              (__bf16)(acc[mb][cb][r] + bv[cb]);
    __syncthreads();
    const int chunk = tid & 3, hh = (tid >> 2) & 1, rbase = tid >> 3;
    const int c_head = c0 + hh*32;
    const int h = (c_head >> 5) & 7;
    __bf16* base = (c_head >> 8) ? Kb : Qb;
    #pragma unroll
    for (int it = 0; it < 4; ++it) {
      int rl = rbase + it*32;
      bf16x8 v = *(const bf16x8*)&Ct[rl*72 + hh*32 + chunk*8];
      *(bf16x8*)&base[((size_t)((bb*HH + h)*NN + n0 + rl))*HD + chunk*8] = v;
    }
  } else {
    __bf16* CtT = (__bf16*)LDSU;
    #pragma unroll
    for (int cb = 0; cb < 4; ++cb)
      #pragma unroll
      for (int mb = 0; mb < 2; ++mb) {
        bf16x4 t;
        #pragma unroll
        for (int r = 0; r < 4; ++r) t[r] = (__bf16)(acc[mb][cb][r] + bv[cb]);
        *(bf16x4*)&CtT[(cb*16 + n16)*136 + w*32 + mb*16 + quad*4] = t;
      }
    __syncthreads();
    const int col = tid >> 2, sg = tid & 3;
    const int c = c0 + col;
    const int h = (c >> 5) & 7, dd = c & 31;
    __bf16* dst = &Vt[((size_t)((bb*HH + h)*HD + dd))*NN + n0 + sg*32];
    const __bf16* srcp = &CtT[col*136 + sg*32];
    #pragma unroll
    for (int q2 = 0; q2 < 4; ++q2)
      *(bf16x8*)&dst[q2*8] = *(const bf16x8*)&srcp[q2*8];
  }
}

// ---------------- fused moire attention (R11: swapped QK^T) ----------------
// S computed as mfma(K, Q): lane (n16,quad) holds S[q = w*16+n16][j = 16cb+4quad+r]
//  -> one q-row per lane: adj loads become float4, mask int4, P pairs pack
//     locally into ds_write_b32, one adj row pointer.
// Ps: [64 rows][128 B], 16B-chunk swizzle byte ^= ((row&7)<<4); conflict-free
//  on writes (banks C ^ m*4 within any phase) and b128 reads (chunk quad^m).
// PV/lacc/epilogue layout unchanged: D rows = q_local -> q = w*16+quad*4+r.
__global__ __launch_bounds__(256, 4) void attn_kernel(
    const __bf16* __restrict__ Q, const __bf16* __restrict__ K,
    const __bf16* __restrict__ Vt, const float* __restrict__ adj,
    const int* __restrict__ mask, const float* __restrict__ shifts,
    const float* __restrict__ widths, const float* __restrict__ slw,
    float* __restrict__ out)
{
  __shared__ __align__(16) char PsU[8192];           // [64][128B] swizzled
  __shared__ __align__(16) __bf16 Ks[2][64][40];     // 10.0 KB double buf
  __shared__ __align__(16) __bf16 Vts[2][32][72];    //  9.0 KB double buf

  const int tid  = threadIdx.x;
  const int w    = tid >> 6, lane = tid & 63;
  const int n16  = lane & 15, quad = lane >> 4;
  const int bh   = blockIdx.x >> 4, qt = blockIdx.x & 15;
  const int b    = bh >> 3, h = bh & 7;
  const int q0   = qt * 64;

  const float L2E   = 1.4426950408889634f;
  const float sh    = shifts[h];
  const float ninvw = -L2E / fmaxf(widths[h], 0.5f);
  const float slv   = slw[h] * L2E;
  const float scl   = 0.17677669529663687f * L2E;
  const float MASKV = -28.0f;   // constant: fully-masked rows stay uniform
  const float c1 = -2.0f * sh * ninvw;
  const float c2 = sh * sh * ninvw;

  const int srow = tid >> 2, sseg = tid & 3;
  const int vd   = tid >> 3, vsg  = tid & 7;

  const __bf16* Kg = K + (size_t)bh*NN*HD;
  const __bf16* Vg = Vt + (size_t)bh*HD*NN;

  // Q fragment straight from global (B-operand of swapped QK^T)
  const bf16x8 qf =
      *(const bf16x8*)&Q[((size_t)bh*NN + q0 + w*16 + n16)*HD + quad*8];

  {  // stage j-tile 0 into buffer 0
    *(bf16x8*)&Ks[0][srow][sseg*8] = *(const bf16x8*)&Kg[srow*HD + sseg*8];
    *(bf16x8*)&Vts[0][vd][vsg*8]   = *(const bf16x8*)&Vg[(size_t)vd*NN + vsg*8];
  }

  const bool mqv = mask[b*NN + q0 + w*16 + n16] != 0;   // single q-mask/lane

  // per-lane adj row pointer (row q = q0 + w*16 + n16), float4 granularity
  const float* aq  = adj + ((size_t)(b*NN + q0 + w*16 + n16))*NN + quad*4;
  const int*   mjp = mask + b*NN + quad*4;

  // adj register double-buffer; preload tile 0
  f32x4 av[2][4];
  #pragma unroll
  for (int cb = 0; cb < 4; ++cb) av[0][cb] = *(const f32x4*)&aq[cb*16];

  // Ps addressing (loop-invariant, LICM-hoisted)
  char* PsRow = PsU + (w*16 + n16)*128;
  const int swzM  = (n16 & 7) * 16;
  const int swzW  = (quad*8) ^ swzM;          // write: (32cb+4h) ^ swzW
  const int swzR0 = (quad*16) ^ swzM;         // read a0
  const int swzR1 = (64 + quad*16) ^ swzM;    // read a1
  const int dloc  = w*16 + n16 - quad*4;      // diag: 16cb + r == dloc

  const f32x4 zero = {0.f, 0.f, 0.f, 0.f};
  f32x4 o0 = zero, o1 = zero, lacc = zero;
  bf16x8 onesb;
  #pragma unroll
  for (int i = 0; i < 8; ++i) onesb[i] = (__bf16)1.0f;

  __syncthreads();

  #pragma unroll 2
  for (int jtl = 0; jtl < 16; ++jtl) {
    const int cur = jtl & 1, nxt = cur ^ 1;
    const int j0  = jtl * 64;

    bf16x8 kn, vn;
    if (jtl < 15) {   // prefetch next K/V tile + next adj tile into regs
      kn = *(const bf16x8*)&Kg[(j0 + 64 + srow)*HD + sseg*8];
      vn = *(const bf16x8*)&Vg[(size_t)vd*NN + j0 + 64 + vsg*8];
      #pragma unroll
      for (int cb = 0; cb < 4; ++cb)
        av[nxt][cb] = *(const f32x4*)&aq[j0 + 64 + cb*16];
    }

    // j-column masks for this tile (L1/L2-hot; issued early, consumed late)
    i32x4 mj[4];
    #pragma unroll
    for (int cb = 0; cb < 4; ++cb) mj[cb] = *(const i32x4*)&mjp[j0 + cb*16];

    f32x4 s[4];
    #pragma unroll
    for (int cb = 0; cb < 4; ++cb) {
      bf16x8 kf = *(const bf16x8*)&Ks[cur][cb*16 + n16][quad*8];
      s[cb] = __builtin_amdgcn_mfma_f32_16x16x32_bf16(kf, qf, zero, 0, 0, 0);
    }

    const bool diagtile = (jtl == qt);   // uniform branch
    #pragma unroll
    for (int cb = 0; cb < 4; ++cb) {
      float p[4];
      #pragma unroll
      for (int r = 0; r < 4; ++r) {
        float a   = av[cur][cb][r];
        float mo  = fmaf(a, fmaf(a, ninvw, c1), c2);   // 2-FMA moire
        float val = fmaf(s[cb][r], scl, mo);
        if (diagtile && (cb*16 + r == dloc)) val += slv;
        bool ok = mqv && (mj[cb][r] != 0);
        val = ok ? val : MASKV;
        p[r] = __builtin_amdgcn_exp2f(val);
      }
      bf16x2 w0, w1;
      w0[0] = (__bf16)p[0]; w0[1] = (__bf16)p[1];
      w1[0] = (__bf16)p[2]; w1[1] = (__bf16)p[3];
      *(bf16x2*)(PsRow + ((cb*32 + 0) ^ swzW)) = w0;
      *(bf16x2*)(PsRow + ((cb*32 + 4) ^ swzW)) = w1;
    }

    bf16x8 a0  = *(const bf16x8*)(PsRow + swzR0);
    bf16x8 a1  = *(const bf16x8*)(PsRow + swzR1);
    bf16x8 b00 = *(const bf16x8*)&Vts[cur][n16][quad*8];
    bf16x8 b01 = *(const bf16x8*)&Vts[cur][n16][32 + quad*8];
    bf16x8 b10 = *(const bf16x8*)&Vts[cur][16 + n16][quad*8];
    bf16x8 b11 = *(const bf16x8*)&Vts[cur][16 + n16][32 + quad*8];
    o0   = __builtin_amdgcn_mfma_f32_16x16x32_bf16(a0, b00, o0, 0, 0, 0);
    o0   = __builtin_amdgcn_mfma_f32_16x16x32_bf16(a1, b01, o0, 0, 0, 0);
    o1   = __builtin_amdgcn_mfma_f32_16x16x32_bf16(a0, b10, o1, 0, 0, 0);
    o1   = __builtin_amdgcn_mfma_f32_16x16x32_bf16(a1, b11, o1, 0, 0, 0);
    // softmax denominator on the matrix pipe: l += P . 1
    lacc = __builtin_amdgcn_mfma_f32_16x16x32_bf16(a0, onesb, lacc, 0, 0, 0);
    lacc = __builtin_amdgcn_mfma_f32_16x16x32_bf16(a1, onesb, lacc, 0, 0, 0);

    if (jtl < 15) {
      *(bf16x8*)&Ks[nxt][srow][sseg*8] = kn;
      *(bf16x8*)&Vts[nxt][vd][vsg*8]   = vn;
    }
    __syncthreads();   // single barrier per j-tile
  }

  #pragma unroll
  for (int r = 0; r < 4; ++r) {
    const float invl = 1.0f / lacc[r];
    const int n = q0 + w*16 + quad*4 + r;
    float* og = out + ((size_t)(b*NN + n))*DM + h*HD;
    og[n16]      = o0[r] * invl;
    og[16 + n16] = o1[r] * invl;
  }
}

extern "C" void kernel_launch(void* const* d_in, const int* in_sizes, int n_in,
                              void* d_out, int out_size, void* d_ws, size_t ws_size,
                              hipStream_t stream) {
  const float* x      = (const float*)d_in[0];
  const float* adj    = (const float*)d_in[1];
  const int*   mask   = (const int*)d_in[2];
  const float* W      = (const float*)d_in[3];
  const float* bias   = (const float*)d_in[4];
  const float* shifts = (const float*)d_in[5];
  const float* widths = (const float*)d_in[6];
  const float* slwp   = (const float*)d_in[7];
  float* out = (float*)d_out;

  const size_t BHND = (size_t)BB*HH*NN*HD;          // 2,097,152
  const size_t WTN  = (size_t)TC*DM;                // 196,608
  __bf16* xbuf = (__bf16*)d_ws;                      // [8192,256] bf16
  __bf16* Wt   = xbuf + BHND;                        // [768,256] bf16
  __bf16* Qb   = Wt + WTN;                           // [B,H,N,32]
  __bf16* Kb   = Qb + BHND;
  __bf16* Vt   = Kb + BHND;

  precast<<<dim3(48 + (int)(BHND/4/256)), 256, 0, stream>>>(x, W, xbuf, Wt);
  qkv_gemm<<<dim3(TC/64, (BB*NN)/128), 256, 0, stream>>>(xbuf, Wt, bias, Qb, Kb, Vt);
  attn_kernel<<<dim3(BB*HH*16), 256, 0, stream>>>(Qb, Kb, Vt, adj, mask,
                                                  shifts, widths, slwp, out);
}

// Round 3
// 133.794 us; speedup vs baseline: 1.1028x; 1.1028x over previous
//
#include <hip/hip_runtime.h>

#define BB 8
#define NN 1024
#define DM 256
#define HH 8
#define HD 32
#define TC 768   // 3*DM

typedef __bf16 bf16x8 __attribute__((ext_vector_type(8)));
typedef __bf16 bf16x4 __attribute__((ext_vector_type(4)));
typedef float  f32x4  __attribute__((ext_vector_type(4)));
typedef unsigned int u32;

// ---------------- precast: x -> bf16, W -> W^T bf16 ----------------
__global__ __launch_bounds__(256) void precast(
    const float* __restrict__ x, const float* __restrict__ W,
    __bf16* __restrict__ xb, __bf16* __restrict__ Wt)
{
  const int tid = threadIdx.x;
  const int bid = blockIdx.x;
  if (bid < 48) {
    __shared__ __bf16 T[64][65];
    const int ct = bid % 12, kt = bid / 12;
    const int c0 = ct * 64, k0 = kt * 64;
    #pragma unroll
    for (int i = 0; i < 16; ++i) {         // read coalesced along c
      int e = tid + i * 256, kk = e >> 6, cc = e & 63;
      T[cc][kk] = (__bf16)W[(size_t)(k0 + kk) * TC + c0 + cc];
    }
    __syncthreads();
    #pragma unroll
    for (int i = 0; i < 16; ++i) {         // write coalesced along k
      int e = tid + i * 256, cc = e >> 6, kk = e & 63;
      Wt[(size_t)(c0 + cc) * DM + k0 + kk] = T[cc][kk];
    }
  } else {
    const size_t e = (size_t)(bid - 48) * 256 + tid;   // float4 index
    const float4 v = ((const float4*)x)[e];
    bf16x4 o;
    o[0] = (__bf16)v.x; o[1] = (__bf16)v.y;
    o[2] = (__bf16)v.z; o[3] = (__bf16)v.w;
    ((bf16x4*)xb)[e] = o;
  }
}

// ---------------- QKV projection: global_load_lds + BK=64 ------------------
__global__ __launch_bounds__(256, 3) void qkv_gemm(
    const __bf16* __restrict__ xb, const __bf16* __restrict__ Wt,
    const float* __restrict__ bias, __bf16* __restrict__ Qb,
    __bf16* __restrict__ Kb, __bf16* __restrict__ Vt)
{
  __shared__ __align__(16) char LDSU[49152];
  __bf16* As0 = (__bf16*)LDSU;             // 16 KB
  __bf16* Bs0 = (__bf16*)(LDSU + 16384);   //  8 KB
  __bf16* As1 = (__bf16*)(LDSU + 24576);   // 16 KB
  __bf16* Bs1 = (__bf16*)(LDSU + 40960);   //  8 KB

  const int tid  = threadIdx.x;
  const int w    = tid >> 6, lane = tid & 63;
  const int n16  = lane & 15, quad = lane >> 4;
  const int m0   = blockIdx.y * 128, c0 = blockIdx.x * 64;
  const int bb   = m0 >> 10, n0 = m0 & 1023;

  const int stRow = w*8 + (lane >> 3);
  const int stG   = (lane & 7) ^ (lane >> 3);
  const __bf16* gA = &xb[(size_t)(m0 + stRow)*DM + stG*8];
  const __bf16* gB = &Wt[(size_t)(c0 + stRow)*DM + stG*8];

#define QKV_STAGE(Adst, Bdst, K0) do {                                        \
    _Pragma("unroll")                                                         \
    for (int i_ = 0; i_ < 4; ++i_) {                                          \
      const __bf16* gp_ = gA + (size_t)(i_*32)*DM + (K0);                     \
      __bf16* lp_ = (Adst) + (i_*32 + w*8)*64;                                \
      __builtin_amdgcn_global_load_lds(                                       \
          (const __attribute__((address_space(1))) u32*)gp_,                  \
          (__attribute__((address_space(3))) u32*)lp_, 16, 0, 0);             \
    }                                                                         \
    _Pragma("unroll")                                                         \
    for (int i_ = 0; i_ < 2; ++i_) {                                          \
      const __bf16* gp_ = gB + (size_t)(i_*32)*DM + (K0);                     \
      __bf16* lp_ = (Bdst) + (i_*32 + w*8)*64;                                \
      __builtin_amdgcn_global_load_lds(                                       \
          (const __attribute__((address_space(1))) u32*)gp_,                  \
          (__attribute__((address_space(3))) u32*)lp_, 16, 0, 0);             \
    }                                                                         \
  } while (0)

  f32x4 acc[2][4] = {};

  QKV_STAGE(As0, Bs0, 0);
  __syncthreads();

  #pragma unroll
  for (int kk = 0; kk < 4; ++kk) {
    __bf16* Ac = (kk & 1) ? As1 : As0;
    __bf16* Bc = (kk & 1) ? Bs1 : Bs0;
    if (kk == 0)      QKV_STAGE(As1, Bs1, 64);
    else if (kk == 1) QKV_STAGE(As0, Bs0, 128);
    else if (kk == 2) QKV_STAGE(As1, Bs1, 192);
    #pragma unroll
    for (int ks = 0; ks < 2; ++ks) {
      const int ch = ((ks*4 + quad) ^ (n16 & 7)) * 8;   // bf16 offset in row
      bf16x8 af0 = *(const bf16x8*)&Ac[(w*32 + n16)*64 + ch];
      bf16x8 af1 = *(const bf16x8*)&Ac[(w*32 + 16 + n16)*64 + ch];
      #pragma unroll
      for (int cb = 0; cb < 4; ++cb) {
        bf16x8 bfb = *(const bf16x8*)&Bc[(cb*16 + n16)*64 + ch];
        acc[0][cb] = __builtin_amdgcn_mfma_f32_16x16x32_bf16(af0, bfb, acc[0][cb], 0, 0, 0);
        acc[1][cb] = __builtin_amdgcn_mfma_f32_16x16x32_bf16(af1, bfb, acc[1][cb], 0, 0, 0);
      }
    }
    __syncthreads();
  }

  float bv[4];
  #pragma unroll
  for (int cb = 0; cb < 4; ++cb) bv[cb] = bias[c0 + cb*16 + n16];

  if (c0 < 512) {
    __bf16* Ct = (__bf16*)LDSU;
    #pragma unroll
    for (int cb = 0; cb < 4; ++cb)
      #pragma unroll
      for (int mb = 0; mb < 2; ++mb)
        #pragma unroll
        for (int r = 0; r < 4; ++r)
          Ct[(w*32 + mb*16 + quad*4 + r)*72 + cb*16 + n16] =
              (__bf16)(acc[mb][cb][r] + bv[cb]);
    __syncthreads();
    const int chunk = tid & 3, hh = (tid >> 2) & 1, rbase = tid >> 3;
    const int c_head = c0 + hh*32;
    const int h = (c_head >> 5) & 7;
    __bf16* base = (c_head >> 8) ? Kb : Qb;
    #pragma unroll
    for (int it = 0; it < 4; ++it) {
      int rl = rbase + it*32;
      bf16x8 v = *(const bf16x8*)&Ct[rl*72 + hh*32 + chunk*8];
      *(bf16x8*)&base[((size_t)((bb*HH + h)*NN + n0 + rl))*HD + chunk*8] = v;
    }
  } else {
    __bf16* CtT = (__bf16*)LDSU;
    #pragma unroll
    for (int cb = 0; cb < 4; ++cb)
      #pragma unroll
      for (int mb = 0; mb < 2; ++mb) {
        bf16x4 t;
        #pragma unroll
        for (int r = 0; r < 4; ++r) t[r] = (__bf16)(acc[mb][cb][r] + bv[cb]);
        *(bf16x4*)&CtT[(cb*16 + n16)*136 + w*32 + mb*16 + quad*4] = t;
      }
    __syncthreads();
    const int col = tid >> 2, sg = tid & 3;
    const int c = c0 + col;
    const int h = (c >> 5) & 7, dd = c & 31;
    __bf16* dst = &Vt[((size_t)((bb*HH + h)*HD + dd))*NN + n0 + sg*32];
    const __bf16* srcp = &CtT[col*136 + sg*32];
    #pragma unroll
    for (int q2 = 0; q2 < 4; ++q2)
      *(bf16x8*)&dst[q2*8] = *(const bf16x8*)&srcp[q2*8];
  }
}

// ---------------- fused moire attention (R12) ------------------------------
// R10 structure (best, 43.4us) + two changes:
//  1. XCD-grouping remap: blockIdx = h*128 + (b*16+qt) -> all 8 heads of one
//     (b,qt) share idx%8 -> same XCD -> 256KB adj tile served 8x from L2.
//  2. Ps = [64][128B], element S[q][j] at byte
//        q*128 + (((j>>3) ^ ((q>>1)&7))<<4) + (j&7)*2
//     Writes: 64 lanes cover all 32 banks at 2/bank (free, m136).
//     Reads (b128): uniform 8/bank (minimum). All addrs loop-invariant.
__global__ __launch_bounds__(256, 4) void attn_kernel(
    const __bf16* __restrict__ Q, const __bf16* __restrict__ K,
    const __bf16* __restrict__ Vt, const float* __restrict__ adj,
    const int* __restrict__ mask, const float* __restrict__ shifts,
    const float* __restrict__ widths, const float* __restrict__ slw,
    float* __restrict__ out)
{
  __shared__ __align__(16) char PsU[8192];           // [64][128B] swizzled
  __shared__ __align__(16) __bf16 Ks[2][64][40];     // 10.0 KB double buf
  __shared__ __align__(16) __bf16 Vts[2][32][72];    //  9.0 KB double buf

  const int tid  = threadIdx.x;
  const int w    = tid >> 6, lane = tid & 63;
  const int n16  = lane & 15, quad = lane >> 4;
  // XCD-grouping decode (change 1)
  const int h    = blockIdx.x >> 7;
  const int lo   = blockIdx.x & 127;
  const int b    = lo >> 4, qt = lo & 15;
  const int bh   = b*8 + h;
  const int q0   = qt * 64;

  const float L2E   = 1.4426950408889634f;
  const float sh    = shifts[h];
  const float ninvw = -L2E / fmaxf(widths[h], 0.5f);
  const float slv   = slw[h] * L2E;
  const float scl   = 0.17677669529663687f * L2E;
  const float MASKV = -28.0f;   // constant: fully-masked rows stay uniform
  const float c1 = -2.0f * sh * ninvw;
  const float c2 = sh * sh * ninvw;

  const int srow = tid >> 2, sseg = tid & 3;
  const int vd   = tid >> 3, vsg  = tid & 7;

  const __bf16* Kg = K + (size_t)bh*NN*HD;
  const __bf16* Vg = Vt + (size_t)bh*HD*NN;

  // Q fragment straight from global (coalesced 16B/lane)
  const bf16x8 qf =
      *(const bf16x8*)&Q[((size_t)bh*NN + q0 + w*16 + n16)*HD + quad*8];

  {  // stage j-tile 0 into buffer 0
    *(bf16x8*)&Ks[0][srow][sseg*8] = *(const bf16x8*)&Kg[srow*HD + sseg*8];
    *(bf16x8*)&Vts[0][vd][vsg*8]   = *(const bf16x8*)&Vg[(size_t)vd*NN + vsg*8];
  }
  int mq[4];
  #pragma unroll
  for (int r = 0; r < 4; ++r) mq[r] = mask[b*NN + q0 + w*16 + quad*4 + r];

  // strength-reduced, lane-resolved adj row pointers (bumped +64 per tile)
  const float* arow0 = adj + ((size_t)(b*NN + q0 + w*16 + quad*4))*NN + n16;
  const float* arow1 = arow0 + NN;
  const float* arow2 = arow0 + 2*NN;
  const float* arow3 = arow0 + 3*NN;
  const int*   mrp   = mask + b*NN + n16;

  // adj/mask register double-buffer; preload tile 0
  float av[2][4][4];
  int   mj[2][4];
  #pragma unroll
  for (int cb = 0; cb < 4; ++cb) mj[0][cb] = mrp[cb*16];
  #pragma unroll
  for (int cb = 0; cb < 4; ++cb) {
    av[0][0][cb] = arow0[cb*16];
    av[0][1][cb] = arow1[cb*16];
    av[0][2][cb] = arow2[cb*16];
    av[0][3][cb] = arow3[cb*16];
  }
  arow0 += 64; arow1 += 64; arow2 += 64; arow3 += 64; mrp += 64;

  // ---- Ps swizzled addresses (change 2) — all loop-invariant ----
  const int w16q4 = w*16 + quad*4;           // rows w16q4 .. w16q4+3 (writes)
  const int hi    = n16 >> 3;                // chunk bit0 from j
  const int lo2   = (n16 & 7) * 2;           // byte within chunk
  const int S01   = (w16q4 >> 1) & 7;        // swizzle key rows r=0,1
  const int S23   = ((w16q4 >> 1) + 1) & 7;  // swizzle key rows r=2,3
  char* PsW01[4]; char* PsW23[4];
  #pragma unroll
  for (int cb = 0; cb < 4; ++cb) {
    PsW01[cb] = PsU + (size_t)w16q4*128     + ((((2*cb + hi) ^ S01) << 4) + lo2);
    PsW23[cb] = PsU + (size_t)(w16q4+2)*128 + ((((2*cb + hi) ^ S23) << 4) + lo2);
  }
  const int rowR = w*16 + n16;               // read row
  const int SR   = (n16 >> 1) & 7;
  const char* PsR0 = PsU + (size_t)rowR*128 + (((quad ^ SR)    ) << 4);
  const char* PsR1 = PsU + (size_t)rowR*128 + (((quad ^ SR) ^ 4) << 4);

  const f32x4 zero = {0.f, 0.f, 0.f, 0.f};
  f32x4 o0 = zero, o1 = zero, lacc = zero;
  bf16x8 onesb;
  #pragma unroll
  for (int i = 0; i < 8; ++i) onesb[i] = (__bf16)1.0f;

  __syncthreads();

  #pragma unroll 2
  for (int jtl = 0; jtl < 16; ++jtl) {
    const int cur = jtl & 1, nxt = cur ^ 1;
    const int j0  = jtl * 64;

    bf16x8 kn, vn;
    if (jtl < 15) {   // prefetch next K/V tile + next adj/mask tile into regs
      kn = *(const bf16x8*)&Kg[(j0 + 64 + srow)*HD + sseg*8];
      vn = *(const bf16x8*)&Vg[(size_t)vd*NN + j0 + 64 + vsg*8];
      #pragma unroll
      for (int cb = 0; cb < 4; ++cb) mj[nxt][cb] = mrp[cb*16];
      #pragma unroll
      for (int cb = 0; cb < 4; ++cb) {
        av[nxt][0][cb] = arow0[cb*16];
        av[nxt][1][cb] = arow1[cb*16];
        av[nxt][2][cb] = arow2[cb*16];
        av[nxt][3][cb] = arow3[cb*16];
      }
      arow0 += 64; arow1 += 64; arow2 += 64; arow3 += 64; mrp += 64;
    }

    f32x4 s[4];
    #pragma unroll
    for (int cb = 0; cb < 4; ++cb) {
      bf16x8 kf = *(const bf16x8*)&Ks[cur][cb*16 + n16][quad*8];
      s[cb] = __builtin_amdgcn_mfma_f32_16x16x32_bf16(qf, kf, zero, 0, 0, 0);
    }

    const bool diagtile = (jtl == qt);   // uniform branch
    #pragma unroll
    for (int r = 0; r < 4; ++r) {
      const int rowl = w16q4 + r;
      #pragma unroll
      for (int cb = 0; cb < 4; ++cb) {
        float a   = av[cur][r][cb];
        float mo  = fmaf(a, fmaf(a, ninvw, c1), c2);   // 2-FMA moire
        float val = fmaf(s[cb][r], scl, mo);
        if (diagtile && (cb*16 + n16 == rowl)) val += slv;
        bool ok = (mq[r] != 0) && (mj[cur][cb] != 0);
        val = ok ? val : MASKV;
        float p = __builtin_amdgcn_exp2f(val);
        char* wp = (r < 2 ? PsW01[cb] : PsW23[cb]) + (r & 1) * 128;
        *(__bf16*)wp = (__bf16)p;
      }
    }

    bf16x8 a0  = *(const bf16x8*)PsR0;
    bf16x8 a1  = *(const bf16x8*)PsR1;
    bf16x8 b00 = *(const bf16x8*)&Vts[cur][n16][quad*8];
    bf16x8 b01 = *(const bf16x8*)&Vts[cur][n16][32 + quad*8];
    bf16x8 b10 = *(const bf16x8*)&Vts[cur][16 + n16][quad*8];
    bf16x8 b11 = *(const bf16x8*)&Vts[cur][16 + n16][32 + quad*8];
    o0   = __builtin_amdgcn_mfma_f32_16x16x32_bf16(a0, b00, o0, 0, 0, 0);
    o0   = __builtin_amdgcn_mfma_f32_16x16x32_bf16(a1, b01, o0, 0, 0, 0);
    o1   = __builtin_amdgcn_mfma_f32_16x16x32_bf16(a0, b10, o1, 0, 0, 0);
    o1   = __builtin_amdgcn_mfma_f32_16x16x32_bf16(a1, b11, o1, 0, 0, 0);
    // softmax denominator on the matrix pipe: l += P . 1
    lacc = __builtin_amdgcn_mfma_f32_16x16x32_bf16(a0, onesb, lacc, 0, 0, 0);
    lacc = __builtin_amdgcn_mfma_f32_16x16x32_bf16(a1, onesb, lacc, 0, 0, 0);

    if (jtl < 15) {
      *(bf16x8*)&Ks[nxt][srow][sseg*8] = kn;
      *(bf16x8*)&Vts[nxt][vd][vsg*8]   = vn;
    }
    __syncthreads();   // single barrier per j-tile
  }

  #pragma unroll
  for (int r = 0; r < 4; ++r) {
    const float invl = 1.0f / lacc[r];
    const int n = q0 + w*16 + quad*4 + r;
    float* og = out + ((size_t)(b*NN + n))*DM + h*HD;
    og[n16]      = o0[r] * invl;
    og[16 + n16] = o1[r] * invl;
  }
}

extern "C" void kernel_launch(void* const* d_in, const int* in_sizes, int n_in,
                              void* d_out, int out_size, void* d_ws, size_t ws_size,
                              hipStream_t stream) {
  const float* x      = (const float*)d_in[0];
  const float* adj    = (const float*)d_in[1];
  const int*   mask   = (const int*)d_in[2];
  const float* W      = (const float*)d_in[3];
  const float* bias   = (const float*)d_in[4];
  const float* shifts = (const float*)d_in[5];
  const float* widths = (const float*)d_in[6];
  const float* slwp   = (const float*)d_in[7];
  float* out = (float*)d_out;

  const size_t BHND = (size_t)BB*HH*NN*HD;          // 2,097,152
  const size_t WTN  = (size_t)TC*DM;                // 196,608
  __bf16* xbuf = (__bf16*)d_ws;                      // [8192,256] bf16
  __bf16* Wt   = xbuf + BHND;                        // [768,256] bf16
  __bf16* Qb   = Wt + WTN;                           // [B,H,N,32]
  __bf16* Kb   = Qb + BHND;
  __bf16* Vt   = Kb + BHND;

  precast<<<dim3(48 + (int)(BHND/4/256)), 256, 0, stream>>>(x, W, xbuf, Wt);
  qkv_gemm<<<dim3(TC/64, (BB*NN)/128), 256, 0, stream>>>(xbuf, Wt, bias, Qb, Kb, Vt);
  attn_kernel<<<dim3(BB*HH*16), 256, 0, stream>>>(Qb, Kb, Vt, adj, mask,
                                                  shifts, widths, slwp, out);
}